// Round 6
// baseline (685.614 us; speedup 1.0000x reference)
//
#include <hip/hip_runtime.h>
#include <hip/hip_bf16.h>

#define D 96
typedef long long i64;

// ---- index-width detection: int64 storage => all high words of first 2048 edges are 0 ----
__global__ __launch_bounds__(64) void k_detect(const unsigned* __restrict__ w, int* flag) {
  unsigned acc = 0;
  int lane = threadIdx.x;
  for (int i = lane; i < 2048; i += 64) acc |= w[2 * i + 1];
#pragma unroll
  for (int off = 32; off > 0; off >>= 1) acc |= __shfl_down(acc, off, 64);
  if (lane == 0) *flag = (acc == 0) ? 1 : 0;  // 1 => int64 storage
}

__global__ __launch_bounds__(256) void k_zero(int* p, int N) {
  int i = blockIdx.x * 256 + threadIdx.x;
  if (i < N) p[i] = 0;
}

// ---- histogram of dst (integer atomics) ----
__global__ __launch_bounds__(256) void k_hist(const int* __restrict__ e32,
                                              const i64* __restrict__ e64,
                                              const int* __restrict__ flagp,
                                              int* cnt, int E, int N) {
  int i = blockIdx.x * 256 + threadIdx.x;
  if (i >= E) return;
  int f = *flagp;
  int d = f ? (int)e64[(size_t)E + i] : e32[(size_t)E + i];
  if ((unsigned)d < (unsigned)N) atomicAdd(&cnt[d], 1);
}

// ---- dinv from counts: deg = in-degree + 1 (self-loop) ----
__global__ __launch_bounds__(256) void k_dinv(const int* __restrict__ cnt, float* dinv, int N) {
  int i = blockIdx.x * 256 + threadIdx.x;
  if (i < N) dinv[i] = rsqrtf((float)cnt[i] + 1.0f);
}

// ---- exclusive scan of cnt -> off (and reset cursor=off); single block 1024 ----
__global__ __launch_bounds__(1024) void k_scan(int* __restrict__ cur, int* __restrict__ off, int N) {
  __shared__ int tmp[1024];
  __shared__ int run;
  int tid = threadIdx.x;
  if (tid == 0) run = 0;
  __syncthreads();
  for (int base = 0; base < N; base += 1024) {
    int i = base + tid;
    int v = (i < N) ? cur[i] : 0;
    tmp[tid] = v;
    __syncthreads();
    for (int s = 1; s < 1024; s <<= 1) {
      int add = (tid >= s) ? tmp[tid - s] : 0;
      __syncthreads();
      tmp[tid] += add;
      __syncthreads();
    }
    int ex = run + tmp[tid] - v;  // exclusive
    if (i < N) { off[i] = ex; cur[i] = ex; }
    __syncthreads();
    if (tid == 1023) run += tmp[1023];
    __syncthreads();
  }
  if (tid == 0) off[N] = run;
}

// ---- fill CSR: csr[pos] = src, pos via integer atomic cursor ----
__global__ __launch_bounds__(256) void k_fill(const int* __restrict__ e32,
                                              const i64* __restrict__ e64,
                                              const int* __restrict__ flagp,
                                              int* cur, int* __restrict__ csr, int E, int N) {
  int i = blockIdx.x * 256 + threadIdx.x;
  if (i >= E) return;
  int f = *flagp;
  int s = f ? (int)e64[i] : e32[i];
  int d = f ? (int)e64[(size_t)E + i] : e32[(size_t)E + i];
  if ((unsigned)s >= (unsigned)N || (unsigned)d >= (unsigned)N) return;
  int pos = atomicAdd(&cur[d], 1);
  csr[pos] = s;
}

// ---- GEMM: t[i,:] = dinv[i] * (A[i,:] @ W) ----
// MODE 0: A = x | MODE 1: A = [x_gcn | h_prev] | MODE 2: A = [x_gcn | g*h_prev]
template <int KTOT, int MODE>
__global__ __launch_bounds__(256) void gemm_kernel(
    const float* __restrict__ xin, const float* __restrict__ xg,
    const float* __restrict__ hprev, const float* __restrict__ gmul,
    const float* __restrict__ W, const float* __restrict__ dinv,
    float* __restrict__ t, int N) {
  __shared__ float As[32][68];
  __shared__ float Ws[32][96];
  const int tid = threadIdx.x;
  const int tx = tid & 15;   // col group (6 cols)
  const int ty = tid >> 4;   // row group (4 rows)
  const int row0 = blockIdx.x * 64;
  float acc[4][6] = {};

  for (int kc = 0; kc < KTOT; kc += 32) {
#pragma unroll
    for (int i = 0; i < 8; i++) {
      int e = tid + i * 256;
      int r = e >> 5, k = e & 31;
      int grow = row0 + r, gk = kc + k;
      float v = 0.0f;
      if (grow < N) {
        if (MODE == 0) {
          v = xin[(size_t)grow * D + gk];
        } else if (gk < 96) {
          v = xg[(size_t)grow * D + gk];
        } else {
          float hv = hprev[(size_t)grow * D + (gk - 96)];
          if (MODE == 2) hv *= gmul[(size_t)grow * D + (gk - 96)];
          v = hv;
        }
      }
      As[k][r] = v;
    }
#pragma unroll
    for (int i = 0; i < 12; i++) {
      int e = tid + i * 256;
      int k = e / 96, c = e - k * 96;
      Ws[k][c] = W[(size_t)(kc + k) * D + c];
    }
    __syncthreads();
#pragma unroll
    for (int k = 0; k < 32; k++) {
      float a[4], b[6];
#pragma unroll
      for (int r = 0; r < 4; r++) a[r] = As[k][ty * 4 + r];
#pragma unroll
      for (int c = 0; c < 6; c++) b[c] = Ws[k][tx * 6 + c];
#pragma unroll
      for (int r = 0; r < 4; r++)
#pragma unroll
        for (int c = 0; c < 6; c++) acc[r][c] += a[r] * b[c];
    }
    __syncthreads();
  }
#pragma unroll
  for (int r = 0; r < 4; r++) {
    int grow = row0 + ty * 4 + r;
    if (grow >= N) continue;
    float dv = dinv[grow];
#pragma unroll
    for (int c = 0; c < 6; c++) {
      int gc = tx * 6 + c;
      t[(size_t)grow * D + gc] = acc[r][c] * dv;
    }
  }
}

// ---- fused gather-reduce + finalize: one node per 128-thread block, no atomics ----
// acc[v,c] = t[v,c] + sum_{e: dst=v} t[src_e, c];  z = dinv[v]*acc + bias[c]
// MODE 1: xgcn = z | MODE 2: g = sigmoid(z) | MODE 3: out = u*hp + (1-u)*tanh(z)  (f32 out!)
template <int MODE>
__global__ __launch_bounds__(128) void gather_fin(
    const float* __restrict__ t, const float* __restrict__ dinv,
    const int* __restrict__ off, const int* __restrict__ csr,
    const float* __restrict__ bias,
    const float* __restrict__ g, const float* __restrict__ hprev,
    float* __restrict__ outf, int N) {
  int v = blockIdx.x;
  int c = threadIdx.x;
  if (v >= N || c >= D) return;
  float acc = t[(size_t)v * D + c];  // self-loop term
  int b0 = off[v], b1 = off[v + 1];
  for (int j = b0; j < b1; j++) {
    int s = csr[j];
    acc += t[(size_t)s * D + c];
  }
  float z = dinv[v] * acc + bias[c];
  size_t idx = (size_t)v * D + c;
  if (MODE == 1) {
    outf[idx] = z;
  } else if (MODE == 2) {
    outf[idx] = 1.0f / (1.0f + expf(-z));
  } else {
    float cc = tanhf(z);
    float u = g[idx];
    float hp = hprev[idx];
    outf[idx] = u * hp + (1.0f - u) * cc;   // f32 output per harness dtype
  }
}

// ---- launch ----
extern "C" void kernel_launch(void* const* d_in, const int* in_sizes, int n_in,
                              void* d_out, int out_size, void* d_ws, size_t ws_size,
                              hipStream_t stream) {
  const float* x = (const float*)d_in[0];
  const int* ei32 = (const int*)d_in[1];
  const i64* ei64 = (const i64*)d_in[1];
  const unsigned* eiw = (const unsigned*)d_in[1];
  const float* hp = (const float*)d_in[2];
  const float* Wx = (const float*)d_in[3];
  const float* bx = (const float*)d_in[4];
  const float* Wuh = (const float*)d_in[5];
  const float* buh = (const float*)d_in[6];
  const float* Wch = (const float*)d_in[7];
  const float* bch = (const float*)d_in[8];
  float* out = (float*)d_out;   // f32 output (established R5 post-mortem)

  const int N = in_sizes[0] / D;
  const int E = in_sizes[1] / 2;
  const size_t NF = (size_t)N * D;
  const size_t nPad = ((size_t)N + 1023) & ~(size_t)1023;

  char* base = (char*)d_ws;
  int* flag = (int*)base;                        // 256 B
  float* dinv = (float*)(base + 256);            // nPad f32
  int* off = (int*)((char*)dinv + nPad * 4);     // nPad+1 ints
  int* cur = off + nPad + 64;                    // nPad ints (cursor/cnt)
  int* csr = cur + nPad;                         // E ints
  float* t = (float*)((char*)(csr + E) + 256);   // NF f32
  float* xg = t + NF;                            // NF f32
  float* g = xg + NF;                            // NF f32

  const int nbN = (N + 255) / 256;
  const int nbE = (E + 255) / 256;
  const int gb = (N + 63) / 64;

  // CSR build + normalization
  k_detect<<<1, 64, 0, stream>>>(eiw, flag);
  k_zero<<<nbN, 256, 0, stream>>>(cur, N);
  k_hist<<<nbE, 256, 0, stream>>>(ei32, ei64, flag, cur, E, N);
  k_dinv<<<nbN, 256, 0, stream>>>(cur, dinv, N);
  k_scan<<<1, 1024, 0, stream>>>(cur, off, N);
  k_fill<<<nbE, 256, 0, stream>>>(ei32, ei64, flag, cur, csr, E, N);

  // GCN 1: xg = x_gcn
  gemm_kernel<96, 0><<<gb, 256, 0, stream>>>(x, nullptr, nullptr, nullptr, Wx, dinv, t, N);
  gather_fin<1><<<N, 128, 0, stream>>>(t, dinv, off, csr, bx, nullptr, nullptr, xg, N);

  // GCN 2: g = sigmoid(GCN([xg, hp]))
  gemm_kernel<192, 1><<<gb, 256, 0, stream>>>(nullptr, xg, hp, nullptr, Wuh, dinv, t, N);
  gather_fin<2><<<N, 128, 0, stream>>>(t, dinv, off, csr, buh, nullptr, nullptr, g, N);

  // GCN 3: out = g*hp + (1-g)*tanh(GCN([xg, g*hp]))
  gemm_kernel<192, 2><<<gb, 256, 0, stream>>>(nullptr, xg, hp, g, Wch, dinv, t, N);
  gather_fin<3><<<N, 128, 0, stream>>>(t, dinv, off, csr, bch, g, hp, out, N);
}

// Round 7
// 508.055 us; speedup vs baseline: 1.3495x; 1.3495x over previous
//
#include <hip/hip_runtime.h>
#include <hip/hip_bf16.h>

#define D 96
typedef long long i64;

// ---- fused: zero cnt + index-width detection (block 0) ----
__global__ __launch_bounds__(256) void k_zero_detect(int* cur, int N,
                                                     const unsigned* __restrict__ w,
                                                     int* flag, int E) {
  int i = blockIdx.x * 256 + threadIdx.x;
  if (i < N) cur[i] = 0;
  if (blockIdx.x == 0 && threadIdx.x < 64) {
    int lane = threadIdx.x;
    int lim = (E < 2048) ? E : 2048;
    unsigned acc = 0;
    for (int j = lane; j < lim; j += 64) acc |= w[2 * j + 1];
#pragma unroll
    for (int off = 32; off > 0; off >>= 1) acc |= __shfl_down(acc, off, 64);
    if (lane == 0) *flag = (acc == 0) ? 1 : 0;  // 1 => int64 storage
  }
}

// ---- histogram of dst (integer atomics) ----
__global__ __launch_bounds__(256) void k_hist(const int* __restrict__ e32,
                                              const i64* __restrict__ e64,
                                              const int* __restrict__ flagp,
                                              int* cnt, int E, int N) {
  int i = blockIdx.x * 256 + threadIdx.x;
  if (i >= E) return;
  int f = *flagp;
  int d = f ? (int)e64[(size_t)E + i] : e32[(size_t)E + i];
  if ((unsigned)d < (unsigned)N) atomicAdd(&cnt[d], 1);
}

// ---- scan phase 1: per-block exclusive scan of cnt -> off (partial), block sums -> bsum.
//      Fused: dinv[i] = rsqrt(cnt[i]+1). 1024 threads/block. ----
__global__ __launch_bounds__(1024) void k_scan1(const int* __restrict__ cnt,
                                                int* __restrict__ off,
                                                float* __restrict__ dinv,
                                                int* __restrict__ bsum, int N) {
  __shared__ int tmp[1024];
  int tid = threadIdx.x;
  int i = blockIdx.x * 1024 + tid;
  int v = (i < N) ? cnt[i] : 0;
  if (i < N) dinv[i] = rsqrtf((float)v + 1.0f);
  tmp[tid] = v;
  __syncthreads();
  for (int s = 1; s < 1024; s <<= 1) {
    int add = (tid >= s) ? tmp[tid - s] : 0;
    __syncthreads();
    tmp[tid] += add;
    __syncthreads();
  }
  if (i < N) off[i] = tmp[tid] - v;  // exclusive, pre-block-offset
  if (tid == 1023) bsum[blockIdx.x] = tmp[1023];
}

// ---- scan phase 2: exclusive scan of block sums (single block); off[N] = total ----
__global__ __launch_bounds__(1024) void k_scan2(int* __restrict__ bsum, int* __restrict__ off,
                                                int NB, int N) {
  __shared__ int tmp[1024];
  int tid = threadIdx.x;
  int v = (tid < NB) ? bsum[tid] : 0;
  tmp[tid] = v;
  __syncthreads();
  for (int s = 1; s < 1024; s <<= 1) {
    int add = (tid >= s) ? tmp[tid - s] : 0;
    __syncthreads();
    tmp[tid] += add;
    __syncthreads();
  }
  if (tid < NB) bsum[tid] = tmp[tid] - v;
  if (tid == NB - 1) off[N] = tmp[tid];
}

// ---- scan phase 3: add block offsets; cur = off (fill cursor) ----
__global__ __launch_bounds__(1024) void k_scan3(int* __restrict__ off, int* __restrict__ cur,
                                                const int* __restrict__ bsum, int N) {
  int i = blockIdx.x * 1024 + threadIdx.x;
  if (i >= N) return;
  int o = off[i] + bsum[blockIdx.x];
  off[i] = o;
  cur[i] = o;
}

// ---- fill CSR: csr[pos] = src, pos via integer atomic cursor ----
__global__ __launch_bounds__(256) void k_fill(const int* __restrict__ e32,
                                              const i64* __restrict__ e64,
                                              const int* __restrict__ flagp,
                                              int* cur, int* __restrict__ csr, int E, int N) {
  int i = blockIdx.x * 256 + threadIdx.x;
  if (i >= E) return;
  int f = *flagp;
  int s = f ? (int)e64[i] : e32[i];
  int d = f ? (int)e64[(size_t)E + i] : e32[(size_t)E + i];
  if ((unsigned)s >= (unsigned)N || (unsigned)d >= (unsigned)N) return;
  int pos = atomicAdd(&cur[d], 1);
  csr[pos] = s;
}

// ---- GEMM: t[i,:] = dinv[i] * (A[i,:] @ W) ----
// MODE 0: A = x | MODE 1: A = [x_gcn | h_prev] | MODE 2: A = [x_gcn | g*h_prev]
template <int KTOT, int MODE>
__global__ __launch_bounds__(256) void gemm_kernel(
    const float* __restrict__ xin, const float* __restrict__ xg,
    const float* __restrict__ hprev, const float* __restrict__ gmul,
    const float* __restrict__ W, const float* __restrict__ dinv,
    float* __restrict__ t, int N) {
  __shared__ float As[32][68];
  __shared__ float Ws[32][96];
  const int tid = threadIdx.x;
  const int tx = tid & 15;   // col group (6 cols)
  const int ty = tid >> 4;   // row group (4 rows)
  const int row0 = blockIdx.x * 64;
  float acc[4][6] = {};

  for (int kc = 0; kc < KTOT; kc += 32) {
#pragma unroll
    for (int i = 0; i < 8; i++) {
      int e = tid + i * 256;
      int r = e >> 5, k = e & 31;
      int grow = row0 + r, gk = kc + k;
      float v = 0.0f;
      if (grow < N) {
        if (MODE == 0) {
          v = xin[(size_t)grow * D + gk];
        } else if (gk < 96) {
          v = xg[(size_t)grow * D + gk];
        } else {
          float hv = hprev[(size_t)grow * D + (gk - 96)];
          if (MODE == 2) hv *= gmul[(size_t)grow * D + (gk - 96)];
          v = hv;
        }
      }
      As[k][r] = v;
    }
#pragma unroll
    for (int i = 0; i < 12; i++) {
      int e = tid + i * 256;
      int k = e / 96, c = e - k * 96;
      Ws[k][c] = W[(size_t)(kc + k) * D + c];
    }
    __syncthreads();
#pragma unroll
    for (int k = 0; k < 32; k++) {
      float a[4], b[6];
#pragma unroll
      for (int r = 0; r < 4; r++) a[r] = As[k][ty * 4 + r];
#pragma unroll
      for (int c = 0; c < 6; c++) b[c] = Ws[k][tx * 6 + c];
#pragma unroll
      for (int r = 0; r < 4; r++)
#pragma unroll
        for (int c = 0; c < 6; c++) acc[r][c] += a[r] * b[c];
    }
    __syncthreads();
  }
#pragma unroll
  for (int r = 0; r < 4; r++) {
    int grow = row0 + ty * 4 + r;
    if (grow >= N) continue;
    float dv = dinv[grow];
#pragma unroll
    for (int c = 0; c < 6; c++) {
      int gc = tx * 6 + c;
      t[(size_t)grow * D + gc] = acc[r][c] * dv;
    }
  }
}

// ---- fused gather-reduce + finalize, flat (node, float4-chunk) mapping ----
// Each thread owns one float4 chunk of one node's row: v = idx/24, c4 = idx%24.
// 100% lane utilization, dwordx4 loads; csr[j] broadcast across the 24 lanes of a group.
// MODE 1: xgcn = z | MODE 2: g = sigmoid(z) | MODE 3: out = u*hp + (1-u)*tanh(z)
template <int MODE>
__global__ __launch_bounds__(256) void gather_fin(
    const float* __restrict__ t, const float* __restrict__ dinv,
    const int* __restrict__ off, const int* __restrict__ csr,
    const float* __restrict__ bias,
    const float* __restrict__ g, const float* __restrict__ hprev,
    float* __restrict__ outf, int N) {
  int idx = blockIdx.x * 256 + threadIdx.x;
  int total = N * 24;
  if (idx >= total) return;
  int v = idx / 24;
  int c4 = idx - v * 24;
  const float4* t4 = (const float4*)t;
  float4 acc = t4[(size_t)v * 24 + c4];  // self-loop term
  int b0 = off[v], b1 = off[v + 1];
  for (int j = b0; j < b1; j++) {
    int s = csr[j];
    float4 tv = t4[(size_t)s * 24 + c4];
    acc.x += tv.x; acc.y += tv.y; acc.z += tv.z; acc.w += tv.w;
  }
  float dv = dinv[v];
  const float4 b4 = ((const float4*)bias)[c4];
  float4 z;
  z.x = dv * acc.x + b4.x; z.y = dv * acc.y + b4.y;
  z.z = dv * acc.z + b4.z; z.w = dv * acc.w + b4.w;
  if (MODE == 1) {
    ((float4*)outf)[idx] = z;
  } else if (MODE == 2) {
    float4 r;
    r.x = 1.0f / (1.0f + expf(-z.x)); r.y = 1.0f / (1.0f + expf(-z.y));
    r.z = 1.0f / (1.0f + expf(-z.z)); r.w = 1.0f / (1.0f + expf(-z.w));
    ((float4*)outf)[idx] = r;
  } else {
    const float4 u4 = ((const float4*)g)[idx];
    const float4 h4 = ((const float4*)hprev)[idx];
    float4 r;
    r.x = u4.x * h4.x + (1.0f - u4.x) * tanhf(z.x);
    r.y = u4.y * h4.y + (1.0f - u4.y) * tanhf(z.y);
    r.z = u4.z * h4.z + (1.0f - u4.z) * tanhf(z.z);
    r.w = u4.w * h4.w + (1.0f - u4.w) * tanhf(z.w);
    ((float4*)outf)[idx] = r;
  }
}

// ---- launch ----
extern "C" void kernel_launch(void* const* d_in, const int* in_sizes, int n_in,
                              void* d_out, int out_size, void* d_ws, size_t ws_size,
                              hipStream_t stream) {
  const float* x = (const float*)d_in[0];
  const int* ei32 = (const int*)d_in[1];
  const i64* ei64 = (const i64*)d_in[1];
  const unsigned* eiw = (const unsigned*)d_in[1];
  const float* hp = (const float*)d_in[2];
  const float* Wx = (const float*)d_in[3];
  const float* bx = (const float*)d_in[4];
  const float* Wuh = (const float*)d_in[5];
  const float* buh = (const float*)d_in[6];
  const float* Wch = (const float*)d_in[7];
  const float* bch = (const float*)d_in[8];
  float* out = (float*)d_out;   // f32 output (established R5)

  const int N = in_sizes[0] / D;
  const int E = in_sizes[1] / 2;
  const size_t NF = (size_t)N * D;
  const size_t nPad = ((size_t)N + 1023) & ~(size_t)1023;
  const size_t ePad = ((size_t)E + 63) & ~(size_t)63;

  char* base = (char*)d_ws;
  int* flag = (int*)base;                        // 256 B
  float* dinv = (float*)(base + 256);            // nPad f32
  int* off = (int*)((char*)dinv + nPad * 4);     // nPad + 64 ints
  int* cur = off + nPad + 64;                    // nPad ints (cnt/cursor)
  int* bsum = cur + nPad;                        // 1024 ints
  int* csr = bsum + 1024;                        // ePad ints
  float* t = (float*)(csr + ePad);               // NF f32 (16B-aligned: all offsets mult of 16)
  float* xg = t + NF;                            // NF f32
  float* g = xg + NF;                            // NF f32

  const int nbN = (N + 255) / 256;
  const int nbE = (E + 255) / 256;
  const int NB = (N + 1023) / 1024;              // scan blocks (<=1024 supported)
  const int gb = (N + 63) / 64;
  const int fb4 = (N * 24 + 255) / 256;

  // CSR build + normalization (multi-block scan, dinv fused into phase 1)
  k_zero_detect<<<nbN, 256, 0, stream>>>(cur, N, eiw, flag, E);
  k_hist<<<nbE, 256, 0, stream>>>(ei32, ei64, flag, cur, E, N);
  k_scan1<<<NB, 1024, 0, stream>>>(cur, off, dinv, bsum, N);
  k_scan2<<<1, 1024, 0, stream>>>(bsum, off, NB, N);
  k_scan3<<<NB, 1024, 0, stream>>>(off, cur, bsum, N);
  k_fill<<<nbE, 256, 0, stream>>>(ei32, ei64, flag, cur, csr, E, N);

  // GCN 1: xg = x_gcn
  gemm_kernel<96, 0><<<gb, 256, 0, stream>>>(x, nullptr, nullptr, nullptr, Wx, dinv, t, N);
  gather_fin<1><<<fb4, 256, 0, stream>>>(t, dinv, off, csr, bx, nullptr, nullptr, xg, N);

  // GCN 2: g = sigmoid(GCN([xg, hp]))
  gemm_kernel<192, 1><<<gb, 256, 0, stream>>>(nullptr, xg, hp, nullptr, Wuh, dinv, t, N);
  gather_fin<2><<<fb4, 256, 0, stream>>>(t, dinv, off, csr, buh, nullptr, nullptr, g, N);

  // GCN 3: out = g*hp + (1-g)*tanh(GCN([xg, g*hp]))
  gemm_kernel<192, 2><<<gb, 256, 0, stream>>>(nullptr, xg, hp, g, Wch, dinv, t, N);
  gather_fin<3><<<fb4, 256, 0, stream>>>(t, dinv, off, csr, bch, g, hp, out, N);
}

// Round 8
// 438.466 us; speedup vs baseline: 1.5637x; 1.1587x over previous
//
#include <hip/hip_runtime.h>
#include <hip/hip_bf16.h>

#define D 96
typedef long long i64;

// ---- fused: zero cnt + index-width detection (block 0) ----
__global__ __launch_bounds__(256) void k_zero_detect(int* cur, int N,
                                                     const unsigned* __restrict__ w,
                                                     int* flag, int E) {
  int i = blockIdx.x * 256 + threadIdx.x;
  if (i < N) cur[i] = 0;
  if (blockIdx.x == 0 && threadIdx.x < 64) {
    int lane = threadIdx.x;
    int lim = (E < 2048) ? E : 2048;
    unsigned acc = 0;
    for (int j = lane; j < lim; j += 64) acc |= w[2 * j + 1];
#pragma unroll
    for (int off = 32; off > 0; off >>= 1) acc |= __shfl_down(acc, off, 64);
    if (lane == 0) *flag = (acc == 0) ? 1 : 0;  // 1 => int64 storage
  }
}

// ---- histogram of dst (integer atomics) ----
__global__ __launch_bounds__(256) void k_hist(const int* __restrict__ e32,
                                              const i64* __restrict__ e64,
                                              const int* __restrict__ flagp,
                                              int* cnt, int E, int N) {
  int i = blockIdx.x * 256 + threadIdx.x;
  if (i >= E) return;
  int f = *flagp;
  int d = f ? (int)e64[(size_t)E + i] : e32[(size_t)E + i];
  if ((unsigned)d < (unsigned)N) atomicAdd(&cnt[d], 1);
}

// ---- scan phase 1: per-block exclusive scan; fused dinv = rsqrt(cnt+1) ----
__global__ __launch_bounds__(1024) void k_scan1(const int* __restrict__ cnt,
                                                int* __restrict__ off,
                                                float* __restrict__ dinv,
                                                int* __restrict__ bsum, int N) {
  __shared__ int tmp[1024];
  int tid = threadIdx.x;
  int i = blockIdx.x * 1024 + tid;
  int v = (i < N) ? cnt[i] : 0;
  if (i < N) dinv[i] = rsqrtf((float)v + 1.0f);
  tmp[tid] = v;
  __syncthreads();
  for (int s = 1; s < 1024; s <<= 1) {
    int add = (tid >= s) ? tmp[tid - s] : 0;
    __syncthreads();
    tmp[tid] += add;
    __syncthreads();
  }
  if (i < N) off[i] = tmp[tid] - v;
  if (tid == 1023) bsum[blockIdx.x] = tmp[1023];
}

// ---- scan phase 2: scan block sums; off[N] = total ----
__global__ __launch_bounds__(1024) void k_scan2(int* __restrict__ bsum, int* __restrict__ off,
                                                int NB, int N) {
  __shared__ int tmp[1024];
  int tid = threadIdx.x;
  int v = (tid < NB) ? bsum[tid] : 0;
  tmp[tid] = v;
  __syncthreads();
  for (int s = 1; s < 1024; s <<= 1) {
    int add = (tid >= s) ? tmp[tid - s] : 0;
    __syncthreads();
    tmp[tid] += add;
    __syncthreads();
  }
  if (tid < NB) bsum[tid] = tmp[tid] - v;
  if (tid == NB - 1) off[N] = tmp[tid];
}

// ---- scan phase 3: add block offsets; cur = off ----
__global__ __launch_bounds__(1024) void k_scan3(int* __restrict__ off, int* __restrict__ cur,
                                                const int* __restrict__ bsum, int N) {
  int i = blockIdx.x * 1024 + threadIdx.x;
  if (i >= N) return;
  int o = off[i] + bsum[blockIdx.x];
  off[i] = o;
  cur[i] = o;
}

// ---- fill CSR ----
__global__ __launch_bounds__(256) void k_fill(const int* __restrict__ e32,
                                              const i64* __restrict__ e64,
                                              const int* __restrict__ flagp,
                                              int* cur, int* __restrict__ csr, int E, int N) {
  int i = blockIdx.x * 256 + threadIdx.x;
  if (i >= E) return;
  int f = *flagp;
  int s = f ? (int)e64[i] : e32[i];
  int d = f ? (int)e64[(size_t)E + i] : e32[(size_t)E + i];
  if ((unsigned)s >= (unsigned)N || (unsigned)d >= (unsigned)N) return;
  int pos = atomicAdd(&cur[d], 1);
  csr[pos] = s;
}

// ---- GEMM: t[i,:] = dinv[i] * (A[i,:] @ W) -- fully vectorized memory path ----
// MODE 0: A = x | MODE 1: A = [x_gcn | h_prev] | MODE 2: A = [x_gcn | g*h_prev]
// tile 64 rows x 96 cols, 256 threads (16x16), per-thread 4x6.
// A in LDS as [k][row] (stride 68: b128-aligned reads, conflict-free broadcast).
template <int KTOT, int MODE>
__global__ __launch_bounds__(256) void gemm_kernel(
    const float* __restrict__ xin, const float* __restrict__ xg,
    const float* __restrict__ hprev, const float* __restrict__ gmul,
    const float* __restrict__ W, const float* __restrict__ dinv,
    float* __restrict__ t, int N) {
  __shared__ float As[32][68];   // [k][row]; 68*4=272B row stride (16B aligned)
  __shared__ float Ws[32][96];   // [k][col]; 384B stride
  const int tid = threadIdx.x;
  const int tx = tid & 15;       // col group (6 cols)
  const int ty = tid >> 4;       // row group (4 rows)
  const int row0 = blockIdx.x * 64;
  float acc[4][6] = {};

  const int srow = tid >> 3;     // staging: row 0..31 per half (e>>3 over 512)
  const int skf = tid & 7;       // staging: float4 group 0..7 (k = 4*skf)

  for (int kc = 0; kc < KTOT; kc += 32) {
    // ---- stage A: 64 rows x 32 k = 512 float4; 2 per thread; coalesced 128B/row ----
#pragma unroll
    for (int i = 0; i < 2; i++) {
      int row = srow + i * 32;
      int grow = row0 + row;
      int gk = kc + 4 * skf;
      float4 v = make_float4(0.f, 0.f, 0.f, 0.f);
      if (grow < N) {
        if (MODE == 0) {
          v = *(const float4*)&xin[(size_t)grow * D + gk];
        } else if (gk < 96) {
          v = *(const float4*)&xg[(size_t)grow * D + gk];
        } else {
          v = *(const float4*)&hprev[(size_t)grow * D + (gk - 96)];
          if (MODE == 2) {
            float4 gm = *(const float4*)&gmul[(size_t)grow * D + (gk - 96)];
            v.x *= gm.x; v.y *= gm.y; v.z *= gm.z; v.w *= gm.w;
          }
        }
      }
      int k0 = 4 * skf;
      As[k0 + 0][row] = v.x;
      As[k0 + 1][row] = v.y;
      As[k0 + 2][row] = v.z;
      As[k0 + 3][row] = v.w;
    }
    // ---- stage W: 32 k x 96 c = 768 float4; 3 per thread; b128 in+out ----
#pragma unroll
    for (int i = 0; i < 3; i++) {
      int e = tid + i * 256;
      int k = e / 24, c4 = e - k * 24;
      *(float4*)&Ws[k][4 * c4] = *(const float4*)&W[(size_t)(kc + k) * D + 4 * c4];
    }
    __syncthreads();
#pragma unroll
    for (int k = 0; k < 32; k++) {
      float4 a4 = *(const float4*)&As[k][ty * 4];          // ds_read_b128
      float2 b01 = *(const float2*)&Ws[k][tx * 6];         // 3x ds_read_b64
      float2 b23 = *(const float2*)&Ws[k][tx * 6 + 2];
      float2 b45 = *(const float2*)&Ws[k][tx * 6 + 4];
      float a[4] = {a4.x, a4.y, a4.z, a4.w};
      float b[6] = {b01.x, b01.y, b23.x, b23.y, b45.x, b45.y};
#pragma unroll
      for (int r = 0; r < 4; r++)
#pragma unroll
        for (int c = 0; c < 6; c++) acc[r][c] += a[r] * b[c];
    }
    __syncthreads();
  }
#pragma unroll
  for (int r = 0; r < 4; r++) {
    int grow = row0 + ty * 4 + r;
    if (grow >= N) continue;
    float dv = dinv[grow];
#pragma unroll
    for (int c = 0; c < 6; c++) {
      int gc = tx * 6 + c;
      t[(size_t)grow * D + gc] = acc[r][c] * dv;
    }
  }
}

// ---- fused gather-reduce + finalize, flat (node, float4-chunk) mapping ----
template <int MODE>
__global__ __launch_bounds__(256) void gather_fin(
    const float* __restrict__ t, const float* __restrict__ dinv,
    const int* __restrict__ off, const int* __restrict__ csr,
    const float* __restrict__ bias,
    const float* __restrict__ g, const float* __restrict__ hprev,
    float* __restrict__ outf, int N) {
  int idx = blockIdx.x * 256 + threadIdx.x;
  int total = N * 24;
  if (idx >= total) return;
  int v = idx / 24;
  int c4 = idx - v * 24;
  const float4* t4 = (const float4*)t;
  float4 acc = t4[(size_t)v * 24 + c4];  // self-loop term
  int b0 = off[v], b1 = off[v + 1];
  for (int j = b0; j < b1; j++) {
    int s = csr[j];
    float4 tv = t4[(size_t)s * 24 + c4];
    acc.x += tv.x; acc.y += tv.y; acc.z += tv.z; acc.w += tv.w;
  }
  float dv = dinv[v];
  const float4 b4 = ((const float4*)bias)[c4];
  float4 z;
  z.x = dv * acc.x + b4.x; z.y = dv * acc.y + b4.y;
  z.z = dv * acc.z + b4.z; z.w = dv * acc.w + b4.w;
  if (MODE == 1) {
    ((float4*)outf)[idx] = z;
  } else if (MODE == 2) {
    float4 r;
    r.x = 1.0f / (1.0f + expf(-z.x)); r.y = 1.0f / (1.0f + expf(-z.y));
    r.z = 1.0f / (1.0f + expf(-z.z)); r.w = 1.0f / (1.0f + expf(-z.w));
    ((float4*)outf)[idx] = r;
  } else {
    const float4 u4 = ((const float4*)g)[idx];
    const float4 h4 = ((const float4*)hprev)[idx];
    float4 r;
    r.x = u4.x * h4.x + (1.0f - u4.x) * tanhf(z.x);
    r.y = u4.y * h4.y + (1.0f - u4.y) * tanhf(z.y);
    r.z = u4.z * h4.z + (1.0f - u4.z) * tanhf(z.z);
    r.w = u4.w * h4.w + (1.0f - u4.w) * tanhf(z.w);
    ((float4*)outf)[idx] = r;
  }
}

// ---- launch ----
extern "C" void kernel_launch(void* const* d_in, const int* in_sizes, int n_in,
                              void* d_out, int out_size, void* d_ws, size_t ws_size,
                              hipStream_t stream) {
  const float* x = (const float*)d_in[0];
  const int* ei32 = (const int*)d_in[1];
  const i64* ei64 = (const i64*)d_in[1];
  const unsigned* eiw = (const unsigned*)d_in[1];
  const float* hp = (const float*)d_in[2];
  const float* Wx = (const float*)d_in[3];
  const float* bx = (const float*)d_in[4];
  const float* Wuh = (const float*)d_in[5];
  const float* buh = (const float*)d_in[6];
  const float* Wch = (const float*)d_in[7];
  const float* bch = (const float*)d_in[8];
  float* out = (float*)d_out;   // f32 output (established R5)

  const int N = in_sizes[0] / D;
  const int E = in_sizes[1] / 2;
  const size_t NF = (size_t)N * D;
  const size_t nPad = ((size_t)N + 1023) & ~(size_t)1023;
  const size_t ePad = ((size_t)E + 63) & ~(size_t)63;

  char* base = (char*)d_ws;
  int* flag = (int*)base;                        // 256 B
  float* dinv = (float*)(base + 256);            // nPad f32
  int* off = (int*)((char*)dinv + nPad * 4);     // nPad + 64 ints
  int* cur = off + nPad + 64;                    // nPad ints
  int* bsum = cur + nPad;                        // 1024 ints
  int* csr = bsum + 1024;                        // ePad ints
  float* t = (float*)(csr + ePad);               // NF f32 (16B aligned)
  float* xg = t + NF;                            // NF f32
  float* g = xg + NF;                            // NF f32

  const int nbN = (N + 255) / 256;
  const int nbE = (E + 255) / 256;
  const int NB = (N + 1023) / 1024;
  const int gb = (N + 63) / 64;
  const int fb4 = (N * 24 + 255) / 256;

  // CSR build + normalization
  k_zero_detect<<<nbN, 256, 0, stream>>>(cur, N, eiw, flag, E);
  k_hist<<<nbE, 256, 0, stream>>>(ei32, ei64, flag, cur, E, N);
  k_scan1<<<NB, 1024, 0, stream>>>(cur, off, dinv, bsum, N);
  k_scan2<<<1, 1024, 0, stream>>>(bsum, off, NB, N);
  k_scan3<<<NB, 1024, 0, stream>>>(off, cur, bsum, N);
  k_fill<<<nbE, 256, 0, stream>>>(ei32, ei64, flag, cur, csr, E, N);

  // GCN 1: xg = x_gcn
  gemm_kernel<96, 0><<<gb, 256, 0, stream>>>(x, nullptr, nullptr, nullptr, Wx, dinv, t, N);
  gather_fin<1><<<fb4, 256, 0, stream>>>(t, dinv, off, csr, bx, nullptr, nullptr, xg, N);

  // GCN 2: g = sigmoid(GCN([xg, hp]))
  gemm_kernel<192, 1><<<gb, 256, 0, stream>>>(nullptr, xg, hp, nullptr, Wuh, dinv, t, N);
  gather_fin<2><<<fb4, 256, 0, stream>>>(t, dinv, off, csr, buh, nullptr, nullptr, g, N);

  // GCN 3: out = g*hp + (1-g)*tanh(GCN([xg, g*hp]))
  gemm_kernel<192, 2><<<gb, 256, 0, stream>>>(nullptr, xg, hp, g, Wch, dinv, t, N);
  gather_fin<3><<<fb4, 256, 0, stream>>>(t, dinv, off, csr, bch, g, hp, out, N);
}

// Round 9
// 410.239 us; speedup vs baseline: 1.6713x; 1.0688x over previous
//
#include <hip/hip_runtime.h>
#include <hip/hip_bf16.h>

#define D 96
typedef long long i64;

// ---- fused: zero cnt + index-width detection (block 0) ----
__global__ __launch_bounds__(256) void k_zero_detect(int* cur, int N,
                                                     const unsigned* __restrict__ w,
                                                     int* flag, int E) {
  int i = blockIdx.x * 256 + threadIdx.x;
  if (i < N) cur[i] = 0;
  if (blockIdx.x == 0 && threadIdx.x < 64) {
    int lane = threadIdx.x;
    int lim = (E < 2048) ? E : 2048;
    unsigned acc = 0;
    for (int j = lane; j < lim; j += 64) acc |= w[2 * j + 1];
#pragma unroll
    for (int off = 32; off > 0; off >>= 1) acc |= __shfl_down(acc, off, 64);
    if (lane == 0) *flag = (acc == 0) ? 1 : 0;  // 1 => int64 storage
  }
}

// ---- histogram of dst (integer atomics) ----
__global__ __launch_bounds__(256) void k_hist(const int* __restrict__ e32,
                                              const i64* __restrict__ e64,
                                              const int* __restrict__ flagp,
                                              int* cnt, int E, int N) {
  int i = blockIdx.x * 256 + threadIdx.x;
  if (i >= E) return;
  int f = *flagp;
  int d = f ? (int)e64[(size_t)E + i] : e32[(size_t)E + i];
  if ((unsigned)d < (unsigned)N) atomicAdd(&cnt[d], 1);
}

// ---- scan phase 1: per-block exclusive scan; fused dinv = rsqrt(cnt+1) ----
__global__ __launch_bounds__(1024) void k_scan1(const int* __restrict__ cnt,
                                                int* __restrict__ off,
                                                float* __restrict__ dinv,
                                                int* __restrict__ bsum, int N) {
  __shared__ int tmp[1024];
  int tid = threadIdx.x;
  int i = blockIdx.x * 1024 + tid;
  int v = (i < N) ? cnt[i] : 0;
  if (i < N) dinv[i] = rsqrtf((float)v + 1.0f);
  tmp[tid] = v;
  __syncthreads();
  for (int s = 1; s < 1024; s <<= 1) {
    int add = (tid >= s) ? tmp[tid - s] : 0;
    __syncthreads();
    tmp[tid] += add;
    __syncthreads();
  }
  if (i < N) off[i] = tmp[tid] - v;
  if (tid == 1023) bsum[blockIdx.x] = tmp[1023];
}

// ---- scan phase 2: scan block sums; off[N] = total ----
__global__ __launch_bounds__(1024) void k_scan2(int* __restrict__ bsum, int* __restrict__ off,
                                                int NB, int N) {
  __shared__ int tmp[1024];
  int tid = threadIdx.x;
  int v = (tid < NB) ? bsum[tid] : 0;
  tmp[tid] = v;
  __syncthreads();
  for (int s = 1; s < 1024; s <<= 1) {
    int add = (tid >= s) ? tmp[tid - s] : 0;
    __syncthreads();
    tmp[tid] += add;
    __syncthreads();
  }
  if (tid < NB) bsum[tid] = tmp[tid] - v;
  if (tid == NB - 1) off[N] = tmp[tid];
}

// ---- scan phase 3: add block offsets; cur = off ----
__global__ __launch_bounds__(1024) void k_scan3(int* __restrict__ off, int* __restrict__ cur,
                                                const int* __restrict__ bsum, int N) {
  int i = blockIdx.x * 1024 + threadIdx.x;
  if (i >= N) return;
  int o = off[i] + bsum[blockIdx.x];
  off[i] = o;
  cur[i] = o;
}

// ---- fill CSR ----
__global__ __launch_bounds__(256) void k_fill(const int* __restrict__ e32,
                                              const i64* __restrict__ e64,
                                              const int* __restrict__ flagp,
                                              int* cur, int* __restrict__ csr, int E, int N) {
  int i = blockIdx.x * 256 + threadIdx.x;
  if (i >= E) return;
  int f = *flagp;
  int s = f ? (int)e64[i] : e32[i];
  int d = f ? (int)e64[(size_t)E + i] : e32[(size_t)E + i];
  if ((unsigned)s >= (unsigned)N || (unsigned)d >= (unsigned)N) return;
  int pos = atomicAdd(&cur[d], 1);
  csr[pos] = s;
}

// ---- GEMM: t[i,:] = dinv[i] * (A[i,:] @ W) -- vectorized memory path ----
template <int KTOT, int MODE>
__global__ __launch_bounds__(256) void gemm_kernel(
    const float* __restrict__ xin, const float* __restrict__ xg,
    const float* __restrict__ hprev, const float* __restrict__ gmul,
    const float* __restrict__ W, const float* __restrict__ dinv,
    float* __restrict__ t, int N) {
  __shared__ float As[32][68];   // [k][row]; 272B stride (16B aligned)
  __shared__ float Ws[32][96];
  const int tid = threadIdx.x;
  const int tx = tid & 15;
  const int ty = tid >> 4;
  const int row0 = blockIdx.x * 64;
  float acc[4][6] = {};

  const int srow = tid >> 3;
  const int skf = tid & 7;

  for (int kc = 0; kc < KTOT; kc += 32) {
#pragma unroll
    for (int i = 0; i < 2; i++) {
      int row = srow + i * 32;
      int grow = row0 + row;
      int gk = kc + 4 * skf;
      float4 v = make_float4(0.f, 0.f, 0.f, 0.f);
      if (grow < N) {
        if (MODE == 0) {
          v = *(const float4*)&xin[(size_t)grow * D + gk];
        } else if (gk < 96) {
          v = *(const float4*)&xg[(size_t)grow * D + gk];
        } else {
          v = *(const float4*)&hprev[(size_t)grow * D + (gk - 96)];
          if (MODE == 2) {
            float4 gm = *(const float4*)&gmul[(size_t)grow * D + (gk - 96)];
            v.x *= gm.x; v.y *= gm.y; v.z *= gm.z; v.w *= gm.w;
          }
        }
      }
      int k0 = 4 * skf;
      As[k0 + 0][row] = v.x;
      As[k0 + 1][row] = v.y;
      As[k0 + 2][row] = v.z;
      As[k0 + 3][row] = v.w;
    }
#pragma unroll
    for (int i = 0; i < 3; i++) {
      int e = tid + i * 256;
      int k = e / 24, c4 = e - k * 24;
      *(float4*)&Ws[k][4 * c4] = *(const float4*)&W[(size_t)(kc + k) * D + 4 * c4];
    }
    __syncthreads();
#pragma unroll
    for (int k = 0; k < 32; k++) {
      float4 a4 = *(const float4*)&As[k][ty * 4];
      float2 b01 = *(const float2*)&Ws[k][tx * 6];
      float2 b23 = *(const float2*)&Ws[k][tx * 6 + 2];
      float2 b45 = *(const float2*)&Ws[k][tx * 6 + 4];
      float a[4] = {a4.x, a4.y, a4.z, a4.w};
      float b[6] = {b01.x, b01.y, b23.x, b23.y, b45.x, b45.y};
#pragma unroll
      for (int r = 0; r < 4; r++)
#pragma unroll
        for (int c = 0; c < 6; c++) acc[r][c] += a[r] * b[c];
    }
    __syncthreads();
  }
#pragma unroll
  for (int r = 0; r < 4; r++) {
    int grow = row0 + ty * 4 + r;
    if (grow >= N) continue;
    float dv = dinv[grow];
#pragma unroll
    for (int c = 0; c < 6; c++) {
      int gc = tx * 6 + c;
      t[(size_t)grow * D + gc] = acc[r][c] * dv;
    }
  }
}

// ---- fused gather-reduce + finalize: flat (node, float4-chunk) mapping ----
// 4x-unrolled neighbor loop: 4 independent row-loads in flight per thread (MLP).
template <int MODE>
__global__ __launch_bounds__(256) void gather_fin(
    const float* __restrict__ t, const float* __restrict__ dinv,
    const int* __restrict__ off, const int* __restrict__ csr,
    const float* __restrict__ bias,
    const float* __restrict__ g, const float* __restrict__ hprev,
    float* __restrict__ outf, int N) {
  int idx = blockIdx.x * 256 + threadIdx.x;
  int total = N * 24;
  if (idx >= total) return;
  int v = idx / 24;
  int c4 = idx - v * 24;
  const float4* t4 = (const float4*)t;
  float4 acc = t4[(size_t)v * 24 + c4];  // self-loop term
  int b0 = off[v], b1 = off[v + 1];
  int j = b0;
  for (; j + 4 <= b1; j += 4) {
    int s0 = csr[j], s1 = csr[j + 1], s2 = csr[j + 2], s3 = csr[j + 3];
    float4 a0 = t4[(size_t)s0 * 24 + c4];
    float4 a1 = t4[(size_t)s1 * 24 + c4];
    float4 a2 = t4[(size_t)s2 * 24 + c4];
    float4 a3 = t4[(size_t)s3 * 24 + c4];
    acc.x += (a0.x + a1.x) + (a2.x + a3.x);
    acc.y += (a0.y + a1.y) + (a2.y + a3.y);
    acc.z += (a0.z + a1.z) + (a2.z + a3.z);
    acc.w += (a0.w + a1.w) + (a2.w + a3.w);
  }
  for (; j < b1; j++) {
    int s = csr[j];
    float4 tv = t4[(size_t)s * 24 + c4];
    acc.x += tv.x; acc.y += tv.y; acc.z += tv.z; acc.w += tv.w;
  }
  float dv = dinv[v];
  const float4 b4 = ((const float4*)bias)[c4];
  float4 z;
  z.x = dv * acc.x + b4.x; z.y = dv * acc.y + b4.y;
  z.z = dv * acc.z + b4.z; z.w = dv * acc.w + b4.w;
  if (MODE == 1) {
    ((float4*)outf)[idx] = z;
  } else if (MODE == 2) {
    float4 r;
    r.x = 1.0f / (1.0f + expf(-z.x)); r.y = 1.0f / (1.0f + expf(-z.y));
    r.z = 1.0f / (1.0f + expf(-z.z)); r.w = 1.0f / (1.0f + expf(-z.w));
    ((float4*)outf)[idx] = r;
  } else {
    const float4 u4 = ((const float4*)g)[idx];
    const float4 h4 = ((const float4*)hprev)[idx];
    float4 r;
    r.x = u4.x * h4.x + (1.0f - u4.x) * tanhf(z.x);
    r.y = u4.y * h4.y + (1.0f - u4.y) * tanhf(z.y);
    r.z = u4.z * h4.z + (1.0f - u4.z) * tanhf(z.z);
    r.w = u4.w * h4.w + (1.0f - u4.w) * tanhf(z.w);
    ((float4*)outf)[idx] = r;
  }
}

// ---- launch ----
extern "C" void kernel_launch(void* const* d_in, const int* in_sizes, int n_in,
                              void* d_out, int out_size, void* d_ws, size_t ws_size,
                              hipStream_t stream) {
  const float* x = (const float*)d_in[0];
  const int* ei32 = (const int*)d_in[1];
  const i64* ei64 = (const i64*)d_in[1];
  const unsigned* eiw = (const unsigned*)d_in[1];
  const float* hp = (const float*)d_in[2];
  const float* Wx = (const float*)d_in[3];
  const float* bx = (const float*)d_in[4];
  const float* Wuh = (const float*)d_in[5];
  const float* buh = (const float*)d_in[6];
  const float* Wch = (const float*)d_in[7];
  const float* bch = (const float*)d_in[8];
  float* out = (float*)d_out;

  const int N = in_sizes[0] / D;
  const int E = in_sizes[1] / 2;
  const size_t NF = (size_t)N * D;
  const size_t nPad = ((size_t)N + 1023) & ~(size_t)1023;
  const size_t ePad = ((size_t)E + 63) & ~(size_t)63;

  char* base = (char*)d_ws;
  int* flag = (int*)base;                        // 256 B
  float* dinv = (float*)(base + 256);            // nPad f32
  int* off = (int*)((char*)dinv + nPad * 4);     // nPad + 64 ints
  int* cur = off + nPad + 64;                    // nPad ints
  int* bsum = cur + nPad;                        // 1024 ints
  int* csr = bsum + 1024;                        // ePad ints
  float* t = (float*)(csr + ePad);               // NF f32 (16B aligned)
  float* xg = t + NF;                            // NF f32
  float* g = xg + NF;                            // NF f32

  const int nbN = (N + 255) / 256;
  const int nbE = (E + 255) / 256;
  const int NB = (N + 1023) / 1024;
  const int gb = (N + 63) / 64;
  const int fb4 = (N * 24 + 255) / 256;

  // CSR build + normalization
  k_zero_detect<<<nbN, 256, 0, stream>>>(cur, N, eiw, flag, E);
  k_hist<<<nbE, 256, 0, stream>>>(ei32, ei64, flag, cur, E, N);
  k_scan1<<<NB, 1024, 0, stream>>>(cur, off, dinv, bsum, N);
  k_scan2<<<1, 1024, 0, stream>>>(bsum, off, NB, N);
  k_scan3<<<NB, 1024, 0, stream>>>(off, cur, bsum, N);
  k_fill<<<nbE, 256, 0, stream>>>(ei32, ei64, flag, cur, csr, E, N);

  // GCN 1: xg = x_gcn
  gemm_kernel<96, 0><<<gb, 256, 0, stream>>>(x, nullptr, nullptr, nullptr, Wx, dinv, t, N);
  gather_fin<1><<<fb4, 256, 0, stream>>>(t, dinv, off, csr, bx, nullptr, nullptr, xg, N);

  // GCN 2: g = sigmoid(GCN([xg, hp]))
  gemm_kernel<192, 1><<<gb, 256, 0, stream>>>(nullptr, xg, hp, nullptr, Wuh, dinv, t, N);
  gather_fin<2><<<fb4, 256, 0, stream>>>(t, dinv, off, csr, buh, nullptr, nullptr, g, N);

  // GCN 3: out = g*hp + (1-g)*tanh(GCN([xg, g*hp]))
  gemm_kernel<192, 2><<<gb, 256, 0, stream>>>(nullptr, xg, hp, g, Wch, dinv, t, N);
  gather_fin<3><<<fb4, 256, 0, stream>>>(t, dinv, off, csr, bch, g, hp, out, N);
}

// Round 10
// 359.384 us; speedup vs baseline: 1.9077x; 1.1415x over previous
//
#include <hip/hip_runtime.h>
#include <hip/hip_bf16.h>

#define D 96
typedef long long i64;

__device__ __forceinline__ float bf2f(unsigned short u) {
  union { unsigned u; float f; } x; x.u = ((unsigned)u) << 16; return x.f;
}
__device__ __forceinline__ void unpack8(uint4 p, float* a) {
  a[0] = bf2f((unsigned short)(p.x & 0xffff)); a[1] = bf2f((unsigned short)(p.x >> 16));
  a[2] = bf2f((unsigned short)(p.y & 0xffff)); a[3] = bf2f((unsigned short)(p.y >> 16));
  a[4] = bf2f((unsigned short)(p.z & 0xffff)); a[5] = bf2f((unsigned short)(p.z >> 16));
  a[6] = bf2f((unsigned short)(p.w & 0xffff)); a[7] = bf2f((unsigned short)(p.w >> 16));
}

// ---- fused: zero cnt + index-width detection (block 0) ----
__global__ __launch_bounds__(256) void k_zero_detect(int* cur, int N,
                                                     const unsigned* __restrict__ w,
                                                     int* flag, int E) {
  int i = blockIdx.x * 256 + threadIdx.x;
  if (i < N) cur[i] = 0;
  if (blockIdx.x == 0 && threadIdx.x < 64) {
    int lane = threadIdx.x;
    int lim = (E < 2048) ? E : 2048;
    unsigned acc = 0;
    for (int j = lane; j < lim; j += 64) acc |= w[2 * j + 1];
#pragma unroll
    for (int off = 32; off > 0; off >>= 1) acc |= __shfl_down(acc, off, 64);
    if (lane == 0) *flag = (acc == 0) ? 1 : 0;  // 1 => int64 storage
  }
}

// ---- histogram of dst, range-partitioned: range = blockIdx&7 owns dst in [rlo,rhi) ----
// All atomics for a given cnt line issue from one range => single-L2 merge, no write amp.
__global__ __launch_bounds__(256) void k_hist(const int* __restrict__ e32,
                                              const i64* __restrict__ e64,
                                              const int* __restrict__ flagp,
                                              int* cnt, int E, int N) {
  int range = blockIdx.x & 7;
  int sub = blockIdx.x >> 3;
  int B = gridDim.x >> 3;
  int chunk = (E + B - 1) / B;
  int lo = sub * chunk;
  int hi = min(E, lo + chunk);
  int f = *flagp;
  int rlo = (int)(((i64)N * range) >> 3);
  int rhi = (int)(((i64)N * (range + 1)) >> 3);
  for (int i = lo + threadIdx.x; i < hi; i += 256) {
    int d = f ? (int)e64[(size_t)E + i] : e32[(size_t)E + i];
    if (d < rlo || d >= rhi) continue;
    atomicAdd(&cnt[d], 1);
  }
}

// ---- scan phase 1: per-block exclusive scan; fused dinv = rsqrt(cnt+1) ----
__global__ __launch_bounds__(1024) void k_scan1(const int* __restrict__ cnt,
                                                int* __restrict__ off,
                                                float* __restrict__ dinv,
                                                int* __restrict__ bsum, int N) {
  __shared__ int tmp[1024];
  int tid = threadIdx.x;
  int i = blockIdx.x * 1024 + tid;
  int v = (i < N) ? cnt[i] : 0;
  if (i < N) dinv[i] = rsqrtf((float)v + 1.0f);
  tmp[tid] = v;
  __syncthreads();
  for (int s = 1; s < 1024; s <<= 1) {
    int add = (tid >= s) ? tmp[tid - s] : 0;
    __syncthreads();
    tmp[tid] += add;
    __syncthreads();
  }
  if (i < N) off[i] = tmp[tid] - v;
  if (tid == 1023) bsum[blockIdx.x] = tmp[1023];
}

// ---- scan phase 2 ----
__global__ __launch_bounds__(1024) void k_scan2(int* __restrict__ bsum, int* __restrict__ off,
                                                int NB, int N) {
  __shared__ int tmp[1024];
  int tid = threadIdx.x;
  int v = (tid < NB) ? bsum[tid] : 0;
  tmp[tid] = v;
  __syncthreads();
  for (int s = 1; s < 1024; s <<= 1) {
    int add = (tid >= s) ? tmp[tid - s] : 0;
    __syncthreads();
    tmp[tid] += add;
    __syncthreads();
  }
  if (tid < NB) bsum[tid] = tmp[tid] - v;
  if (tid == NB - 1) off[N] = tmp[tid];
}

// ---- scan phase 3 ----
__global__ __launch_bounds__(1024) void k_scan3(int* __restrict__ off, int* __restrict__ cur,
                                                const int* __restrict__ bsum, int N) {
  int i = blockIdx.x * 1024 + threadIdx.x;
  if (i >= N) return;
  int o = off[i] + bsum[blockIdx.x];
  off[i] = o;
  cur[i] = o;
}

// ---- fill CSR, range-partitioned (same scheme as k_hist) ----
__global__ __launch_bounds__(256) void k_fill(const int* __restrict__ e32,
                                              const i64* __restrict__ e64,
                                              const int* __restrict__ flagp,
                                              int* cur, int* __restrict__ csr, int E, int N) {
  int range = blockIdx.x & 7;
  int sub = blockIdx.x >> 3;
  int B = gridDim.x >> 3;
  int chunk = (E + B - 1) / B;
  int lo = sub * chunk;
  int hi = min(E, lo + chunk);
  int f = *flagp;
  int rlo = (int)(((i64)N * range) >> 3);
  int rhi = (int)(((i64)N * (range + 1)) >> 3);
  for (int i = lo + threadIdx.x; i < hi; i += 256) {
    int d = f ? (int)e64[(size_t)E + i] : e32[(size_t)E + i];
    if (d < rlo || d >= rhi) continue;
    int s = f ? (int)e64[i] : e32[i];
    if ((unsigned)s >= (unsigned)N) continue;
    int pos = atomicAdd(&cur[d], 1);
    csr[pos] = s;
  }
}

// ---- GEMM: t[i,:] = bf16( dinv[i] * (A[i,:] @ W) ) ----
// MODE 0: A = x | MODE 1: A = [x_gcn | h_prev] | MODE 2: A = [x_gcn | g*h_prev]
template <int KTOT, int MODE>
__global__ __launch_bounds__(256) void gemm_kernel(
    const float* __restrict__ xin, const float* __restrict__ xg,
    const float* __restrict__ hprev, const float* __restrict__ gmul,
    const float* __restrict__ W, const float* __restrict__ dinv,
    __hip_bfloat16* __restrict__ t, int N) {
  __shared__ float As[32][68];   // [k][row]; 272B stride (16B aligned)
  __shared__ float Ws[32][96];
  const int tid = threadIdx.x;
  const int tx = tid & 15;
  const int ty = tid >> 4;
  const int row0 = blockIdx.x * 64;
  float acc[4][6] = {};

  const int srow = tid >> 3;
  const int skf = tid & 7;

  for (int kc = 0; kc < KTOT; kc += 32) {
#pragma unroll
    for (int i = 0; i < 2; i++) {
      int row = srow + i * 32;
      int grow = row0 + row;
      int gk = kc + 4 * skf;
      float4 v = make_float4(0.f, 0.f, 0.f, 0.f);
      if (grow < N) {
        if (MODE == 0) {
          v = *(const float4*)&xin[(size_t)grow * D + gk];
        } else if (gk < 96) {
          v = *(const float4*)&xg[(size_t)grow * D + gk];
        } else {
          v = *(const float4*)&hprev[(size_t)grow * D + (gk - 96)];
          if (MODE == 2) {
            float4 gm = *(const float4*)&gmul[(size_t)grow * D + (gk - 96)];
            v.x *= gm.x; v.y *= gm.y; v.z *= gm.z; v.w *= gm.w;
          }
        }
      }
      int k0 = 4 * skf;
      As[k0 + 0][row] = v.x;
      As[k0 + 1][row] = v.y;
      As[k0 + 2][row] = v.z;
      As[k0 + 3][row] = v.w;
    }
#pragma unroll
    for (int i = 0; i < 3; i++) {
      int e = tid + i * 256;
      int k = e / 24, c4 = e - k * 24;
      *(float4*)&Ws[k][4 * c4] = *(const float4*)&W[(size_t)(kc + k) * D + 4 * c4];
    }
    __syncthreads();
#pragma unroll
    for (int k = 0; k < 32; k++) {
      float4 a4 = *(const float4*)&As[k][ty * 4];
      float2 b01 = *(const float2*)&Ws[k][tx * 6];
      float2 b23 = *(const float2*)&Ws[k][tx * 6 + 2];
      float2 b45 = *(const float2*)&Ws[k][tx * 6 + 4];
      float a[4] = {a4.x, a4.y, a4.z, a4.w};
      float b[6] = {b01.x, b01.y, b23.x, b23.y, b45.x, b45.y};
#pragma unroll
      for (int r = 0; r < 4; r++)
#pragma unroll
        for (int c = 0; c < 6; c++) acc[r][c] += a[r] * b[c];
    }
    __syncthreads();
  }
#pragma unroll
  for (int r = 0; r < 4; r++) {
    int grow = row0 + ty * 4 + r;
    if (grow >= N) continue;
    float dv = dinv[grow];
#pragma unroll
    for (int c = 0; c < 6; c++) {
      int gc = tx * 6 + c;
      t[(size_t)grow * D + gc] = __float2bfloat16(acc[r][c] * dv);
    }
  }
}

// ---- fused gather-reduce + finalize: bf16 t, 8-elem chunks (12 threads/node) ----
// 4x-unrolled neighbor loop for MLP; accumulate in f32.
template <int MODE>
__global__ __launch_bounds__(256) void gather_fin(
    const __hip_bfloat16* __restrict__ t, const float* __restrict__ dinv,
    const int* __restrict__ off, const int* __restrict__ csr,
    const float* __restrict__ bias,
    const float* __restrict__ g, const float* __restrict__ hprev,
    float* __restrict__ outf, int N) {
  int idx = blockIdx.x * 256 + threadIdx.x;
  int total = N * 12;
  if (idx >= total) return;
  int v = idx / 12;
  int c8 = idx - v * 12;                 // covers cols c8*8 .. c8*8+7
  const uint4* t8 = (const uint4*)t;     // 8 bf16 per uint4; 12 per row
  float acc[8];
  unpack8(t8[(size_t)v * 12 + c8], acc); // self-loop term
  int b0 = off[v], b1 = off[v + 1];
  int j = b0;
  for (; j + 4 <= b1; j += 4) {
    int s0 = csr[j], s1 = csr[j + 1], s2 = csr[j + 2], s3 = csr[j + 3];
    uint4 p0 = t8[(size_t)s0 * 12 + c8];
    uint4 p1 = t8[(size_t)s1 * 12 + c8];
    uint4 p2 = t8[(size_t)s2 * 12 + c8];
    uint4 p3 = t8[(size_t)s3 * 12 + c8];
    float a0[8], a1[8], a2[8], a3[8];
    unpack8(p0, a0); unpack8(p1, a1); unpack8(p2, a2); unpack8(p3, a3);
#pragma unroll
    for (int q = 0; q < 8; q++) acc[q] += (a0[q] + a1[q]) + (a2[q] + a3[q]);
  }
  for (; j < b1; j++) {
    int s = csr[j];
    float a0[8];
    unpack8(t8[(size_t)s * 12 + c8], a0);
#pragma unroll
    for (int q = 0; q < 8; q++) acc[q] += a0[q];
  }
  float dv = dinv[v];
  float4 bA = ((const float4*)bias)[c8 * 2];
  float4 bB = ((const float4*)bias)[c8 * 2 + 1];
  float z[8] = {dv * acc[0] + bA.x, dv * acc[1] + bA.y, dv * acc[2] + bA.z, dv * acc[3] + bA.w,
                dv * acc[4] + bB.x, dv * acc[5] + bB.y, dv * acc[6] + bB.z, dv * acc[7] + bB.w};
  float4 oA, oB;
  if (MODE == 1) {
    oA = make_float4(z[0], z[1], z[2], z[3]);
    oB = make_float4(z[4], z[5], z[6], z[7]);
  } else if (MODE == 2) {
    oA = make_float4(1.0f / (1.0f + expf(-z[0])), 1.0f / (1.0f + expf(-z[1])),
                     1.0f / (1.0f + expf(-z[2])), 1.0f / (1.0f + expf(-z[3])));
    oB = make_float4(1.0f / (1.0f + expf(-z[4])), 1.0f / (1.0f + expf(-z[5])),
                     1.0f / (1.0f + expf(-z[6])), 1.0f / (1.0f + expf(-z[7])));
  } else {
    float4 uA = ((const float4*)g)[idx * 2], uB = ((const float4*)g)[idx * 2 + 1];
    float4 hA = ((const float4*)hprev)[idx * 2], hB = ((const float4*)hprev)[idx * 2 + 1];
    oA = make_float4(uA.x * hA.x + (1.0f - uA.x) * tanhf(z[0]),
                     uA.y * hA.y + (1.0f - uA.y) * tanhf(z[1]),
                     uA.z * hA.z + (1.0f - uA.z) * tanhf(z[2]),
                     uA.w * hA.w + (1.0f - uA.w) * tanhf(z[3]));
    oB = make_float4(uB.x * hB.x + (1.0f - uB.x) * tanhf(z[4]),
                     uB.y * hB.y + (1.0f - uB.y) * tanhf(z[5]),
                     uB.z * hB.z + (1.0f - uB.z) * tanhf(z[6]),
                     uB.w * hB.w + (1.0f - uB.w) * tanhf(z[7]));
  }
  ((float4*)outf)[idx * 2] = oA;
  ((float4*)outf)[idx * 2 + 1] = oB;
}

// ---- launch ----
extern "C" void kernel_launch(void* const* d_in, const int* in_sizes, int n_in,
                              void* d_out, int out_size, void* d_ws, size_t ws_size,
                              hipStream_t stream) {
  const float* x = (const float*)d_in[0];
  const int* ei32 = (const int*)d_in[1];
  const i64* ei64 = (const i64*)d_in[1];
  const unsigned* eiw = (const unsigned*)d_in[1];
  const float* hp = (const float*)d_in[2];
  const float* Wx = (const float*)d_in[3];
  const float* bx = (const float*)d_in[4];
  const float* Wuh = (const float*)d_in[5];
  const float* buh = (const float*)d_in[6];
  const float* Wch = (const float*)d_in[7];
  const float* bch = (const float*)d_in[8];
  float* out = (float*)d_out;

  const int N = in_sizes[0] / D;
  const int E = in_sizes[1] / 2;
  const size_t NF = (size_t)N * D;
  const size_t nPad = ((size_t)N + 1023) & ~(size_t)1023;
  const size_t ePad = ((size_t)E + 63) & ~(size_t)63;

  char* base = (char*)d_ws;
  int* flag = (int*)base;                        // 256 B
  float* dinv = (float*)(base + 256);            // nPad f32
  int* off = (int*)((char*)dinv + nPad * 4);     // nPad + 64 ints
  int* cur = off + nPad + 64;                    // nPad ints
  int* bsum = cur + nPad;                        // 1024 ints
  int* csr = bsum + 1024;                        // ePad ints
  __hip_bfloat16* t = (__hip_bfloat16*)(csr + ePad);  // NF bf16 (16B aligned)
  float* xg = (float*)((char*)t + NF * 2);       // NF f32
  float* g = xg + NF;                            // NF f32

  const int nbN = (N + 255) / 256;
  const int NB = (N + 1023) / 1024;
  const int gb = (N + 63) / 64;
  const int fb8 = (N * 12 + 255) / 256;
  const int pb = 8 * 256;                        // range-partitioned hist/fill grid

  // CSR build + normalization
  k_zero_detect<<<nbN, 256, 0, stream>>>(cur, N, eiw, flag, E);
  k_hist<<<pb, 256, 0, stream>>>(ei32, ei64, flag, cur, E, N);
  k_scan1<<<NB, 1024, 0, stream>>>(cur, off, dinv, bsum, N);
  k_scan2<<<1, 1024, 0, stream>>>(bsum, off, NB, N);
  k_scan3<<<NB, 1024, 0, stream>>>(off, cur, bsum, N);
  k_fill<<<pb, 256, 0, stream>>>(ei32, ei64, flag, cur, csr, E, N);

  // GCN 1: xg = x_gcn
  gemm_kernel<96, 0><<<gb, 256, 0, stream>>>(x, nullptr, nullptr, nullptr, Wx, dinv, t, N);
  gather_fin<1><<<fb8, 256, 0, stream>>>(t, dinv, off, csr, bx, nullptr, nullptr, xg, N);

  // GCN 2: g = sigmoid(GCN([xg, hp]))
  gemm_kernel<192, 1><<<gb, 256, 0, stream>>>(nullptr, xg, hp, nullptr, Wuh, dinv, t, N);
  gather_fin<2><<<fb8, 256, 0, stream>>>(t, dinv, off, csr, buh, nullptr, nullptr, g, N);

  // GCN 3: out = g*hp + (1-g)*tanh(GCN([xg, g*hp]))
  gemm_kernel<192, 2><<<gb, 256, 0, stream>>>(nullptr, xg, hp, g, Wch, dinv, t, N);
  gather_fin<3><<<fb8, 256, 0, stream>>>(t, dinv, off, csr, bch, g, hp, out, N);
}